// Round 4
// baseline (98.827 us; speedup 1.0000x reference)
//
#include <hip/hip_runtime.h>
#include <hip/hip_fp16.h>
#include <stdint.h>

#define HH   56
#define WW   56
#define HWP  3136
#define CC   256
#define GG   16
#define CGR  16
#define KT   7
#define KK   49
#define TH   2
#define XROW 32            // u32 per sXh row (64 f16)
#define XPL  260           // u32 per sXh ch-plane (8*32+4)
#define PBLK 512           // u32 per h2s pxblk: [q4(8)][px16(16)][jj(4)]
#define NPB  196           // pxblks per batch (3136/16)
#define H2SB (4 * NPB * PBLK * 4)   // h2s bytes = 1,605,632

typedef _Float16 h2_t   __attribute__((ext_vector_type(2)));
typedef __fp16   fp16x2 __attribute__((ext_vector_type(2)));
typedef _Float16 v8h    __attribute__((ext_vector_type(8)));
typedef float    v4f    __attribute__((ext_vector_type(4)));
union pk32 { uint32_t u; h2_t h; __half2 hh; fp16x2 f; };
union frag { uint32_t u[4]; v8h h; };

static __device__ __forceinline__ uint32_t pkrtz(float a, float b) {
    pk32 p; p.f = __builtin_amdgcn_cvt_pkrtz(a, b); return p.u;
}

// pack a 32-wide f32 k-segment into an 8xf16 MFMA A-half-fragment
static __device__ __forceinline__ frag pack_afrag(const float* rowp, int quad) {
    frag a;
    const float4 p0 = *(const float4*)&rowp[quad * 8];
    const float4 p1 = *(const float4*)&rowp[quad * 8 + 4];
    a.u[0] = pkrtz(p0.x, p0.y); a.u[1] = pkrtz(p0.z, p0.w);
    a.u[2] = pkrtz(p1.x, p1.y); a.u[3] = pkrtz(p1.z, p1.w);
    return a;
}

// ---- gemm1 via MFMA: M-split, 784 blocks (~3/CU) ---------------------------
// R1's 392-block version left half the CUs idle (grid-limited, 1.53 blocks/CU).
// Split the 64 output channels across blockIdx.y (mh=0: ch 0-31, mh=1: ch 32-63)
// keeping the identical 32-px / 256-thread / 4-wave shape: B staging, xf-store
// coalescing (64B segments) and LDS patterns are bit-identical to R1.
// x is read twice device-wide; second read is L2/L3-served.
__global__ __launch_bounds__(256)
void gemm1_mfma(const float* __restrict__ rw, const float* __restrict__ rb,
                const float* __restrict__ x, uint32_t* __restrict__ h2s,
                uint16_t* __restrict__ xf)
{
    const int b = blockIdx.z, px0 = blockIdx.x * 32, mh = blockIdx.y;
    const int t = threadIdx.x;
    const int wave = t >> 6, lane = t & 63, quad = lane >> 4, n16 = lane & 15;
    const int mt = wave >> 1, nt = wave & 1;   // wave -> (m-tile, n-tile)

    __shared__ __align__(16) uint32_t ldsB[2][1024];  // staging; epilogue reuses as 16x33 transpose

    const int px = t & 31;          // staging: 32 px x 8 q4
    const int q4 = t >> 5;
    const float* xb = x + (size_t)b * CC * HWP + px0 + px;

    // prefetch all 4 K-chunks of B (x) into registers
    float r[4][8];
#pragma unroll
    for (int k = 0; k < 4; ++k)
#pragma unroll
        for (int cc = 0; cc < 8; ++cc)
            r[k][cc] = xb[(size_t)(k * 64 + q4 * 8 + cc) * HWP];

    // pack all 4 K-chunks of A (rw, f32 -> f16) up-front; this block's M-rows
    const float* rwr = rw + (size_t)(mh * 32 + mt * 16 + n16) * CC;
    frag af0[4], af1[4];
#pragma unroll
    for (int k = 0; k < 4; ++k) {
        af0[k] = pack_afrag(rwr + k * 64, quad);
        af1[k] = pack_afrag(rwr + k * 64 + 32, quad);
    }

    {   // stage chunk 0
        uint4 w;
        w.x = pkrtz(r[0][0], r[0][1]); w.y = pkrtz(r[0][2], r[0][3]);
        w.z = pkrtz(r[0][4], r[0][5]); w.w = pkrtz(r[0][6], r[0][7]);
        *(uint4*)&ldsB[0][q4 * 128 + px * 4] = w;
    }
    __syncthreads();

    v4f acc = v4f{0.f,0.f,0.f,0.f};
#pragma unroll
    for (int k = 0; k < 4; ++k) {
        if (k < 3) {    // stage next chunk into other buffer (register source only)
            uint4 w;
            w.x = pkrtz(r[k+1][0], r[k+1][1]); w.y = pkrtz(r[k+1][2], r[k+1][3]);
            w.z = pkrtz(r[k+1][4], r[k+1][5]); w.w = pkrtz(r[k+1][6], r[k+1][7]);
            *(uint4*)&ldsB[(k + 1) & 1][q4 * 128 + px * 4] = w;
        }
        const uint32_t* B = ldsB[k & 1];
        frag b0, b1;
        *(uint4*)b0.u = *(const uint4*)&B[quad * 128 + (nt * 16 + n16) * 4];
        *(uint4*)b1.u = *(const uint4*)&B[(4 + quad) * 128 + (nt * 16 + n16) * 4];
        acc = __builtin_amdgcn_mfma_f32_16x16x32_f16(af0[k].h, b0.h, acc, 0, 0, 0);
        acc = __builtin_amdgcn_mfma_f32_16x16x32_f16(af1[k].h, b1.h, acc, 0, 0, 0);
        __syncthreads();
    }

    // f16 x sidecar: split across the M-split pair (mh 0: chunks 0-1, mh 1: 2-3).
    // k is compile-time (unrolled); condition is wave-uniform -> no dyn reg index.
    {
        uint16_t* xfp = xf + (size_t)b * CC * HWP + px0 + px;
#pragma unroll
        for (int k = 0; k < 4; ++k)
            if ((k >> 1) == mh) {
#pragma unroll
                for (int cc = 0; cc < 8; ++cc) {
                    pk32 p; p.f = __builtin_amdgcn_cvt_pkrtz(r[k][cc], r[k][cc]);
                    xfp[(size_t)(k * 64 + q4 * 8 + cc) * HWP] = (uint16_t)p.u;
                }
            }
    }

    // epilogue: transpose c-pairs through LDS, then b128-coalesced strip-major stores
    uint32_t* ldsT = &ldsB[0][0];                    // 16 x 33 u32 (both buffers dead)
#pragma unroll
    for (int pr = 0; pr < 2; ++pr) {
        const int cpl = mt * 8 + quad * 2 + pr;      // local channel-pair 0..15
        const int cpg = mh * 16 + cpl;               // global channel-pair 0..31
        ldsT[cpl * 33 + nt * 16 + n16] =
            pkrtz(acc[2 * pr] + rb[2 * cpg], acc[2 * pr + 1] + rb[2 * cpg + 1]);
    }
    __syncthreads();
    if (t < 128) {
        const int oq4l = t >> 5, px32 = t & 31;      // local q4 group 0..3
        uint4 w;
        w.x = ldsT[(oq4l * 4 + 0) * 33 + px32];
        w.y = ldsT[(oq4l * 4 + 1) * 33 + px32];
        w.z = ldsT[(oq4l * 4 + 2) * 33 + px32];
        w.w = ldsT[(oq4l * 4 + 3) * 33 + px32];
        uint32_t* hp = h2s + (size_t)b * NPB * PBLK
                     + (size_t)(blockIdx.x * 2 + (px32 >> 4)) * PBLK
                     + (mh * 4 + oq4l) * 64 + (px32 & 15) * 4;
        *(uint4*)hp = w;
    }
}

// ---- fused kern-gen + involution: B-frags direct from global, ONE barrier ---
// LDS: sXh 16.25 KB + sK 10.97 KB = 27.2 KB -> 5 blocks/CU
// Phase C REVERTED to the R1 224-thread version (round-3's 2-ch split regressed:
// kern reads were already wave-broadcast; the split doubled the serial VALU
// chain and halved phase-C wave parallelism).
__global__ __launch_bounds__(256, 5)
void invol_fused(const uint16_t* __restrict__ xf, const uint32_t* __restrict__ h2s,
                 const float* __restrict__ sw, const float* __restrict__ sb,
                 float* __restrict__ out)
{
    const int h0 = blockIdx.x * TH, g = blockIdx.y, b = blockIdx.z;

    __shared__ __align__(16) uint32_t sXh[16 * XPL];   // f16 x, [ch][row][64f16]
    __shared__ __align__(16) uint32_t sK[KK * 56];     // kern f16 [tap][112px]

    const int t = threadIdx.x;
    const int wave = t >> 6, lane = t & 63, quad = lane >> 4, n16 = lane & 15;

    // A-frags packed from f32 sw (wave-uniform row block, L2/L3-hot)
    const int mt0 = wave * 16 + n16;
    const int mtap = mt0 > 48 ? 48 : mt0;
    const float* swr = sw + (size_t)(g * KK + mtap) * 64;
    const frag a0 = pack_afrag(swr, quad);
    const frag a1 = pack_afrag(swr + 32, quad);

    float bvv[4];
#pragma unroll
    for (int reg = 0; reg < 4; ++reg) {
        const int tp = wave * 16 + quad * 4 + reg;
        bvv[reg] = (tp < KK) ? sb[g * KK + tp] : 0.f;
    }

    // sXh: halo zero + own-group interior (f16 sidecar); no barrier until phase C
    {
        const int ch = t >> 4, rr = (t >> 1) & 7, side = t & 1;
        uint2 z; z.x = 0; z.y = 0;
        *(uint2*)&sXh[ch * XPL + rr * XROW + (side ? 30 : 0)] = z;
    }
    {
        const uint16_t* xb = xf + (size_t)(b * CC + g * CGR) * HWP;
#pragma unroll
        for (int k = 0; k < 4; ++k) {
            const int i = t + 256 * k;                  // 896 row-segments total
            if (i < 896) {
                const int u4 = i % 7, row = i / 7;      // row 0..127
                const int ch = row >> 3, rr = row & 7;
                const int hh = h0 - 3 + rr;
                uint4 v; v.x = 0; v.y = 0; v.z = 0; v.w = 0;
                if (hh >= 0 && hh < HH)
                    v = *(const uint4*)&xb[(size_t)ch * HWP + hh * WW + 8 * u4];
                uint32_t* d = &sXh[ch * XPL + rr * XROW + 2 + 4 * u4];
                uint2 p0; p0.x = v.x; p0.y = v.y;
                uint2 p1; p1.x = v.z; p1.y = v.w;
                *(uint2*)&d[0] = p0;
                *(uint2*)&d[2] = p1;
            }
        }
    }

    // MFMA: K[49][112] = SW[49][64] @ H[64][112]; B-frags straight from global h2s
    {
        const uint32_t* hb = h2s + (size_t)b * NPB * PBLK + (size_t)(blockIdx.x * 7) * PBLK;
        v4f acc[7];
#pragma unroll
        for (int nt = 0; nt < 7; ++nt) acc[nt] = v4f{0.f,0.f,0.f,0.f};
#pragma unroll
        for (int nt = 0; nt < 7; ++nt) {
            const uint32_t* pb = hb + nt * PBLK + n16 * 4;
            frag b0, b1;
            *(uint4*)b0.u = *(const uint4*)&pb[quad * 64];
            *(uint4*)b1.u = *(const uint4*)&pb[(4 + quad) * 64];
            acc[nt] = __builtin_amdgcn_mfma_f32_16x16x32_f16(a0.h, b0.h, acc[nt], 0, 0, 0);
            acc[nt] = __builtin_amdgcn_mfma_f32_16x16x32_f16(a1.h, b1.h, acc[nt], 0, 0, 0);
        }
        // epilogue -> sK f16 [tap][112]
        _Float16* sKh = (_Float16*)sK;
#pragma unroll
        for (int nt = 0; nt < 7; ++nt) {
            const int px = nt * 16 + n16;
#pragma unroll
            for (int reg = 0; reg < 4; ++reg) {
                const int tp = wave * 16 + quad * 4 + reg;
                if (tp < KK) sKh[tp * 112 + px] = (_Float16)(acc[nt][reg] + bvv[reg]);
            }
        }
    }
    __syncthreads();                                    // the ONE barrier

    // phase C: t<224, thread = (ch, r, wq), 8 px outputs
    if (t < 224) {
        const int ch = t & 15, q = t >> 4, r = q & 1, wq = q >> 1;
        const uint32_t* xpl = &sXh[ch * XPL + 4 * wq];
        float o0=0,o1=0,o2=0,o3=0,o4=0,o5=0,o6=0,o7=0;
#pragma unroll
        for (int kh = 0; kh < KT; ++kh) {
            const int rr = r + kh;
            uint32_t E[8];
            *(uint4*)&E[0] = *(const uint4*)&xpl[rr * XROW];
            *(uint4*)&E[4] = *(const uint4*)&xpl[rr * XROW + 4];
            uint32_t O[7];
#pragma unroll
            for (int j = 0; j < 7; ++j) O[j] = __builtin_amdgcn_alignbit(E[j + 1], E[j], 16);
            pk32 va0, va1, va2, va3;
            va0.u = va1.u = va2.u = va3.u = 0;
            const uint32_t* kq = &sK[(kh * KT) * 56 + r * 28 + 4 * wq];
#pragma unroll
            for (int kw = 0; kw < KT; ++kw) {
                const uint4 kk = *(const uint4*)&kq[kw * 56];
                pk32 k0, k1, k2, k3; k0.u = kk.x; k1.u = kk.y; k2.u = kk.z; k3.u = kk.w;
                pk32 s0, s1, s2, s3;
                if (kw & 1) {
                    const int e = (kw + 1) >> 1;
                    s0.u = E[e]; s1.u = E[e + 1]; s2.u = E[e + 2]; s3.u = E[e + 3];
                } else {
                    const int oI = kw >> 1;
                    s0.u = O[oI]; s1.u = O[oI + 1]; s2.u = O[oI + 2]; s3.u = O[oI + 3];
                }
                va0.hh = __hfma2(k0.hh, s0.hh, va0.hh);
                va1.hh = __hfma2(k1.hh, s1.hh, va1.hh);
                va2.hh = __hfma2(k2.hh, s2.hh, va2.hh);
                va3.hh = __hfma2(k3.hh, s3.hh, va3.hh);
            }
            const float2 f0 = __half22float2(va0.hh); o0 += f0.x; o1 += f0.y;
            const float2 f1 = __half22float2(va1.hh); o2 += f1.x; o3 += f1.y;
            const float2 f2 = __half22float2(va2.hh); o4 += f2.x; o5 += f2.y;
            const float2 f3 = __half22float2(va3.hh); o6 += f3.x; o7 += f3.y;
        }
        float* op = out + (size_t)(b * CC + g * CGR + ch) * HWP + (h0 + r) * WW + 8 * wq;
        *(float4*)&op[0] = make_float4(o0, o1, o2, o3);
        *(float4*)&op[4] = make_float4(o4, o5, o6, o7);
    }
}

extern "C" void kernel_launch(void* const* d_in, const int* in_sizes, int n_in,
                              void* d_out, int out_size, void* d_ws, size_t ws_size,
                              hipStream_t stream)
{
    const float* x  = (const float*)d_in[0];   // (4,256,56,56)
    const float* rw = (const float*)d_in[1];   // (64,256)
    const float* rb = (const float*)d_in[2];   // (64,)
    const float* sw = (const float*)d_in[3];   // (784,64)
    const float* sb = (const float*)d_in[4];   // (784,)
    float* out  = (float*)d_out;               // (4,256,56,56)

    uint32_t* h2s = (uint32_t*)d_ws;                          // 1.6 MB, B-frag order
    uint16_t* xf  = (uint16_t*)((char*)d_ws + H2SB);          // 6.4 MB f16 x sidecar

    gemm1_mfma<<<dim3(HWP / 32, 2, 4), 256, 0, stream>>>(rw, rb, x, h2s, xf);
    invol_fused<<<dim3(HH / TH, GG, 4), 256, 0, stream>>>(xf, h2s, sw, sb, out);
}

// Round 5
// 92.994 us; speedup vs baseline: 1.0627x; 1.0627x over previous
//
#include <hip/hip_runtime.h>
#include <hip/hip_fp16.h>
#include <stdint.h>

#define HH   56
#define WW   56
#define HWP  3136
#define CC   256
#define GG   16
#define CGR  16
#define KT   7
#define KK   49
#define TH   2
#define XROW 32            // u32 per sXh row (64 f16)
#define XPL  260           // u32 per sXh ch-plane (8*32+4)
#define PBLK 512           // u32 per h2s pxblk: [q4(8)][px16(16)][jj(4)]
#define NPB  196           // pxblks per batch (3136/16)
#define H2SB (4 * NPB * PBLK * 4)   // h2s bytes = 1,605,632

typedef _Float16 h2_t   __attribute__((ext_vector_type(2)));
typedef __fp16   fp16x2 __attribute__((ext_vector_type(2)));
typedef _Float16 v8h    __attribute__((ext_vector_type(8)));
typedef float    v4f    __attribute__((ext_vector_type(4)));
union pk32 { uint32_t u; h2_t h; __half2 hh; fp16x2 f; };
union frag { uint32_t u[4]; v8h h; };

static __device__ __forceinline__ uint32_t pkrtz(float a, float b) {
    pk32 p; p.f = __builtin_amdgcn_cvt_pkrtz(a, b); return p.u;
}

// pack a 32-wide f32 k-segment into an 8xf16 MFMA A-half-fragment
static __device__ __forceinline__ frag pack_afrag(const float* rowp, int quad) {
    frag a;
    const float4 p0 = *(const float4*)&rowp[quad * 8];
    const float4 p1 = *(const float4*)&rowp[quad * 8 + 4];
    a.u[0] = pkrtz(p0.x, p0.y); a.u[1] = pkrtz(p0.z, p0.w);
    a.u[2] = pkrtz(p1.x, p1.y); a.u[3] = pkrtz(p1.z, p1.w);
    return a;
}

// ---- gemm1 via MFMA: R1 champion, verbatim ---------------------------------
// 32 px / 256 threads / 392 blocks. Staging-throughput-bound: per-block B-stage
// work amortizes over 16 MFMAs. Both split variants (R2 px-split, R4 M-split)
// regressed by doubling device-wide staging work — do not restructure.
__global__ __launch_bounds__(256)
void gemm1_mfma(const float* __restrict__ rw, const float* __restrict__ rb,
                const float* __restrict__ x, uint32_t* __restrict__ h2s,
                uint16_t* __restrict__ xf)
{
    const int b = blockIdx.z, px0 = blockIdx.x * 32;
    const int t = threadIdx.x;
    const int wave = t >> 6, lane = t & 63, quad = lane >> 4, n16 = lane & 15;

    __shared__ __align__(16) uint32_t ldsB[2][1024];  // staging; epilogue reuses as 32x33 transpose

    const int px = t & 31;          // staging: 32 px x 8 q4
    const int q4 = t >> 5;
    const float* xb = x + (size_t)b * CC * HWP + px0 + px;

    // prefetch all 4 K-chunks of B (x) into registers
    float r[4][8];
#pragma unroll
    for (int k = 0; k < 4; ++k)
#pragma unroll
        for (int cc = 0; cc < 8; ++cc)
            r[k][cc] = xb[(size_t)(k * 64 + q4 * 8 + cc) * HWP];

    // pack all 4 K-chunks of A (rw, f32 -> f16) up-front
    const float* rwr = rw + (size_t)(wave * 16 + n16) * CC;
    frag af0[4], af1[4];
#pragma unroll
    for (int k = 0; k < 4; ++k) {
        af0[k] = pack_afrag(rwr + k * 64, quad);
        af1[k] = pack_afrag(rwr + k * 64 + 32, quad);
    }

    {   // stage chunk 0
        uint4 w;
        w.x = pkrtz(r[0][0], r[0][1]); w.y = pkrtz(r[0][2], r[0][3]);
        w.z = pkrtz(r[0][4], r[0][5]); w.w = pkrtz(r[0][6], r[0][7]);
        *(uint4*)&ldsB[0][q4 * 128 + px * 4] = w;
    }
    __syncthreads();

    v4f acc[2];
    acc[0] = v4f{0.f,0.f,0.f,0.f}; acc[1] = v4f{0.f,0.f,0.f,0.f};
#pragma unroll
    for (int k = 0; k < 4; ++k) {
        if (k < 3) {    // stage next chunk into other buffer (register source only)
            uint4 w;
            w.x = pkrtz(r[k+1][0], r[k+1][1]); w.y = pkrtz(r[k+1][2], r[k+1][3]);
            w.z = pkrtz(r[k+1][4], r[k+1][5]); w.w = pkrtz(r[k+1][6], r[k+1][7]);
            *(uint4*)&ldsB[(k + 1) & 1][q4 * 128 + px * 4] = w;
        }
        const uint32_t* B = ldsB[k & 1];
#pragma unroll
        for (int nt = 0; nt < 2; ++nt) {
            frag b0, b1;
            *(uint4*)b0.u = *(const uint4*)&B[quad * 128 + (nt * 16 + n16) * 4];
            *(uint4*)b1.u = *(const uint4*)&B[(4 + quad) * 128 + (nt * 16 + n16) * 4];
            acc[nt] = __builtin_amdgcn_mfma_f32_16x16x32_f16(af0[k].h, b0.h, acc[nt], 0, 0, 0);
            acc[nt] = __builtin_amdgcn_mfma_f32_16x16x32_f16(af1[k].h, b1.h, acc[nt], 0, 0, 0);
        }
        __syncthreads();
    }

    // f16 x sidecar: r[][] holds all 256 ch for this thread's px.
    {
        uint16_t* xfp = xf + (size_t)b * CC * HWP + px0 + px;
#pragma unroll
        for (int k = 0; k < 4; ++k)
#pragma unroll
            for (int cc = 0; cc < 8; ++cc) {
                pk32 p; p.f = __builtin_amdgcn_cvt_pkrtz(r[k][cc], r[k][cc]);
                xfp[(size_t)(k * 64 + q4 * 8 + cc) * HWP] = (uint16_t)p.u;
            }
    }

    // epilogue: transpose c-pairs through LDS, then b128-coalesced strip-major stores
    uint32_t* ldsT = &ldsB[0][0];                    // 32 x 33 u32 (both buffers dead)
#pragma unroll
    for (int nt = 0; nt < 2; ++nt)
#pragma unroll
        for (int pr = 0; pr < 2; ++pr) {
            const int cp = wave * 8 + quad * 2 + pr; // channel-pair 0..31
            ldsT[cp * 33 + nt * 16 + n16] =
                pkrtz(acc[nt][2 * pr] + rb[2 * cp], acc[nt][2 * pr + 1] + rb[2 * cp + 1]);
        }
    __syncthreads();
    {
        const int oq4 = t >> 5, px32 = t & 31;
        uint4 w;
        w.x = ldsT[(oq4 * 4 + 0) * 33 + px32];
        w.y = ldsT[(oq4 * 4 + 1) * 33 + px32];
        w.z = ldsT[(oq4 * 4 + 2) * 33 + px32];
        w.w = ldsT[(oq4 * 4 + 3) * 33 + px32];
        uint32_t* hp = h2s + (size_t)b * NPB * PBLK
                     + (size_t)(blockIdx.x * 2 + (px32 >> 4)) * PBLK
                     + oq4 * 64 + (px32 & 15) * 4;
        *(uint4*)hp = w;
    }
}

// ---- fused kern-gen + involution: R1 champion + XCD-locality swizzle -------
// LDS: sXh 16.25 KB + sK 10.97 KB = 27.2 KB -> 5 blocks/CU
// Grid flattened to 1792 = 8 XCD x 224; swz = (bid&7)*224 + bid>>3 gives each
// XCD contiguous 28-h0 chains (8 full (g,b) chains): adjacent-h0 blocks share
// 6/8 staged xf rows and same-h0 blocks across g share h2s pxblks -> both
// become XCD-L2-local instead of 4x HBM re-fetch (T1, m204 bijective form).
__global__ __launch_bounds__(256, 5)
void invol_fused(const uint16_t* __restrict__ xf, const uint32_t* __restrict__ h2s,
                 const float* __restrict__ sw, const float* __restrict__ sb,
                 float* __restrict__ out)
{
    const int bid = blockIdx.x;                 // 0..1791
    const int swz = (bid & 7) * 224 + (bid >> 3);
    const int hb  = swz % 28;                   // h0-block, fastest within chunk
    const int g   = (swz / 28) & 15;
    const int b   = swz / 448;
    const int h0  = hb * TH;

    __shared__ __align__(16) uint32_t sXh[16 * XPL];   // f16 x, [ch][row][64f16]
    __shared__ __align__(16) uint32_t sK[KK * 56];     // kern f16 [tap][112px]

    const int t = threadIdx.x;
    const int wave = t >> 6, lane = t & 63, quad = lane >> 4, n16 = lane & 15;

    // A-frags packed from f32 sw (wave-uniform row block, L2/L3-hot)
    const int mt0 = wave * 16 + n16;
    const int mtap = mt0 > 48 ? 48 : mt0;
    const float* swr = sw + (size_t)(g * KK + mtap) * 64;
    const frag a0 = pack_afrag(swr, quad);
    const frag a1 = pack_afrag(swr + 32, quad);

    float bvv[4];
#pragma unroll
    for (int reg = 0; reg < 4; ++reg) {
        const int tp = wave * 16 + quad * 4 + reg;
        bvv[reg] = (tp < KK) ? sb[g * KK + tp] : 0.f;
    }

    // sXh: halo zero + own-group interior (f16 sidecar); no barrier until phase C
    {
        const int ch = t >> 4, rr = (t >> 1) & 7, side = t & 1;
        uint2 z; z.x = 0; z.y = 0;
        *(uint2*)&sXh[ch * XPL + rr * XROW + (side ? 30 : 0)] = z;
    }
    {
        const uint16_t* xb = xf + (size_t)(b * CC + g * CGR) * HWP;
#pragma unroll
        for (int k = 0; k < 4; ++k) {
            const int i = t + 256 * k;                  // 896 row-segments total
            if (i < 896) {
                const int u4 = i % 7, row = i / 7;      // row 0..127
                const int ch = row >> 3, rr = row & 7;
                const int hh = h0 - 3 + rr;
                uint4 v; v.x = 0; v.y = 0; v.z = 0; v.w = 0;
                if (hh >= 0 && hh < HH)
                    v = *(const uint4*)&xb[(size_t)ch * HWP + hh * WW + 8 * u4];
                uint32_t* d = &sXh[ch * XPL + rr * XROW + 2 + 4 * u4];
                uint2 p0; p0.x = v.x; p0.y = v.y;
                uint2 p1; p1.x = v.z; p1.y = v.w;
                *(uint2*)&d[0] = p0;
                *(uint2*)&d[2] = p1;
            }
        }
    }

    // MFMA: K[49][112] = SW[49][64] @ H[64][112]; B-frags straight from global h2s
    {
        const uint32_t* hb2 = h2s + (size_t)b * NPB * PBLK + (size_t)(hb * 7) * PBLK;
        v4f acc[7];
#pragma unroll
        for (int nt = 0; nt < 7; ++nt) acc[nt] = v4f{0.f,0.f,0.f,0.f};
#pragma unroll
        for (int nt = 0; nt < 7; ++nt) {
            const uint32_t* pb = hb2 + nt * PBLK + n16 * 4;
            frag b0, b1;
            *(uint4*)b0.u = *(const uint4*)&pb[quad * 64];
            *(uint4*)b1.u = *(const uint4*)&pb[(4 + quad) * 64];
            acc[nt] = __builtin_amdgcn_mfma_f32_16x16x32_f16(a0.h, b0.h, acc[nt], 0, 0, 0);
            acc[nt] = __builtin_amdgcn_mfma_f32_16x16x32_f16(a1.h, b1.h, acc[nt], 0, 0, 0);
        }
        // epilogue -> sK f16 [tap][112]
        _Float16* sKh = (_Float16*)sK;
#pragma unroll
        for (int nt = 0; nt < 7; ++nt) {
            const int px = nt * 16 + n16;
#pragma unroll
            for (int reg = 0; reg < 4; ++reg) {
                const int tp = wave * 16 + quad * 4 + reg;
                if (tp < KK) sKh[tp * 112 + px] = (_Float16)(acc[nt][reg] + bvv[reg]);
            }
        }
    }
    __syncthreads();                                    // the ONE barrier

    // phase C: t<224, thread = (ch, r, wq), 8 px outputs
    if (t < 224) {
        const int ch = t & 15, q = t >> 4, r = q & 1, wq = q >> 1;
        const uint32_t* xpl = &sXh[ch * XPL + 4 * wq];
        float o0=0,o1=0,o2=0,o3=0,o4=0,o5=0,o6=0,o7=0;
#pragma unroll
        for (int kh = 0; kh < KT; ++kh) {
            const int rr = r + kh;
            uint32_t E[8];
            *(uint4*)&E[0] = *(const uint4*)&xpl[rr * XROW];
            *(uint4*)&E[4] = *(const uint4*)&xpl[rr * XROW + 4];
            uint32_t O[7];
#pragma unroll
            for (int j = 0; j < 7; ++j) O[j] = __builtin_amdgcn_alignbit(E[j + 1], E[j], 16);
            pk32 va0, va1, va2, va3;
            va0.u = va1.u = va2.u = va3.u = 0;
            const uint32_t* kq = &sK[(kh * KT) * 56 + r * 28 + 4 * wq];
#pragma unroll
            for (int kw = 0; kw < KT; ++kw) {
                const uint4 kk = *(const uint4*)&kq[kw * 56];
                pk32 k0, k1, k2, k3; k0.u = kk.x; k1.u = kk.y; k2.u = kk.z; k3.u = kk.w;
                pk32 s0, s1, s2, s3;
                if (kw & 1) {
                    const int e = (kw + 1) >> 1;
                    s0.u = E[e]; s1.u = E[e + 1]; s2.u = E[e + 2]; s3.u = E[e + 3];
                } else {
                    const int oI = kw >> 1;
                    s0.u = O[oI]; s1.u = O[oI + 1]; s2.u = O[oI + 2]; s3.u = O[oI + 3];
                }
                va0.hh = __hfma2(k0.hh, s0.hh, va0.hh);
                va1.hh = __hfma2(k1.hh, s1.hh, va1.hh);
                va2.hh = __hfma2(k2.hh, s2.hh, va2.hh);
                va3.hh = __hfma2(k3.hh, s3.hh, va3.hh);
            }
            const float2 f0 = __half22float2(va0.hh); o0 += f0.x; o1 += f0.y;
            const float2 f1 = __half22float2(va1.hh); o2 += f1.x; o3 += f1.y;
            const float2 f2 = __half22float2(va2.hh); o4 += f2.x; o5 += f2.y;
            const float2 f3 = __half22float2(va3.hh); o6 += f3.x; o7 += f3.y;
        }
        float* op = out + (size_t)(b * CC + g * CGR + ch) * HWP + (h0 + r) * WW + 8 * wq;
        *(float4*)&op[0] = make_float4(o0, o1, o2, o3);
        *(float4*)&op[4] = make_float4(o4, o5, o6, o7);
    }
}

extern "C" void kernel_launch(void* const* d_in, const int* in_sizes, int n_in,
                              void* d_out, int out_size, void* d_ws, size_t ws_size,
                              hipStream_t stream)
{
    const float* x  = (const float*)d_in[0];   // (4,256,56,56)
    const float* rw = (const float*)d_in[1];   // (64,256)
    const float* rb = (const float*)d_in[2];   // (64,)
    const float* sw = (const float*)d_in[3];   // (784,64)
    const float* sb = (const float*)d_in[4];   // (784,)
    float* out  = (float*)d_out;               // (4,256,56,56)

    uint32_t* h2s = (uint32_t*)d_ws;                          // 1.6 MB, B-frag order
    uint16_t* xf  = (uint16_t*)((char*)d_ws + H2SB);          // 6.4 MB f16 x sidecar

    gemm1_mfma<<<dim3(HWP / 32, 1, 4), 256, 0, stream>>>(rw, rb, x, h2s, xf);
    invol_fused<<<dim3(28 * GG * 4, 1, 1), 256, 0, stream>>>(xf, h2s, sw, sb, out);
}